// Round 1
// baseline (506.475 us; speedup 1.0000x reference)
//
#include <hip/hip_runtime.h>

typedef unsigned short u16;
typedef float f32x4 __attribute__((ext_vector_type(4)));
typedef __bf16 bf16x8 __attribute__((ext_vector_type(8)));

// ---------- bf16 helpers (RNE) ----------
__device__ __forceinline__ u16 f2bf(float f) {
    unsigned u = __float_as_uint(f);
    u += 0x7FFFu + ((u >> 16) & 1u);
    return (u16)(u >> 16);
}
__device__ __forceinline__ float b2f(u16 h) {
    return __uint_as_float(((unsigned)h) << 16);
}

// ---------- async global->LDS, 16B per lane, wave-uniform LDS base ----------
__device__ __forceinline__ void async16(const u16* g, u16* l) {
    __builtin_amdgcn_global_load_lds(
        (__attribute__((address_space(1))) void*)(u16*)g,
        (__attribute__((address_space(3))) void*)l,
        16, 0, 0);
}

#define T_TOK 4096
#define DIM   2048

// ---------- weight fp32 -> bf16 cast, vectorized ----------
__global__ __launch_bounds__(256) void castw_kernel(const float* __restrict__ src,
                                                    u16* __restrict__ dst, int n4) {
    int i = blockIdx.x * 256 + threadIdx.x;
    if (i < n4) {
        float4 f = ((const float4*)src)[i];
        ushort4 u;
        u.x = f2bf(f.x); u.y = f2bf(f.y); u.z = f2bf(f.z); u.w = f2bf(f.w);
        ((ushort4*)dst)[i] = u;
    }
}

// ---------- LayerNorm + bf16 cast; one block per token ----------
__global__ __launch_bounds__(256) void ln_cast_kernel(const float* __restrict__ x,
                                                      const float* __restrict__ g,
                                                      const float* __restrict__ b,
                                                      u16* __restrict__ o) {
    __shared__ float s1[4], s2[4];
    int t = blockIdx.x, tid = threadIdx.x;
    int wave = tid >> 6, lane = tid & 63;
    size_t base = (size_t)t * DIM;
    float v[8];
    float s = 0.f;
#pragma unroll
    for (int j = 0; j < 8; ++j) { v[j] = x[base + j * 256 + tid]; s += v[j]; }
#pragma unroll
    for (int o2 = 32; o2; o2 >>= 1) s += __shfl_xor(s, o2);
    if (lane == 0) s1[wave] = s;
    __syncthreads();
    float mu = (s1[0] + s1[1] + s1[2] + s1[3]) * (1.f / DIM);
    float q = 0.f;
#pragma unroll
    for (int j = 0; j < 8; ++j) { float d = v[j] - mu; q += d * d; }
#pragma unroll
    for (int o2 = 32; o2; o2 >>= 1) q += __shfl_xor(q, o2);
    if (lane == 0) s2[wave] = q;
    __syncthreads();
    float var = (s2[0] + s2[1] + s2[2] + s2[3]) * (1.f / DIM);
    float rs = rsqrtf(var + 1e-5f);
#pragma unroll
    for (int j = 0; j < 8; ++j) {
        int d = j * 256 + tid;
        o[base + d] = f2bf((v[j] - mu) * rs * g[d] + b[d]);
    }
}

// ---------- GEMM: C[m,n] = sum_k A[m,k] * W[n,k]  (both row-major bf16) ----------
// 128x128 tile, BK=32, 256 threads = 4 waves (2x2), each wave 4x4 x mfma 16x16x32.
// EPI: 0 = bias + bf16 store; 1 = bias + min(softplus,1) + bf16; 2 = bias + resid + f32.
#define BM 128
#define BN 128
#define BK 32

template <int EPI>
__global__ __launch_bounds__(256) void gemm_bt(const u16* __restrict__ A, int lda,
                                               const u16* __restrict__ W,
                                               const float* __restrict__ bias,
                                               const float* __restrict__ resid,
                                               void* __restrict__ C, int ldc, int K) {
    __shared__ __align__(16) u16 lAB[2 * BM * BK];  // 16 KB: [A 128x32 | W 128x32]
    const int tid = threadIdx.x;
    const int wave = tid >> 6, lane = tid & 63;
    const int quad = lane >> 4, l16 = lane & 15;
    const int tM = blockIdx.x * BM;
    const int tN = blockIdx.y * BN;
    const int wr = wave >> 1, wc = wave & 1;

    // staging: 16 chunks of 1KB; wave w owns chunks w*4..w*4+3. chunks 0-7 = A, 8-15 = W.
    const bool isB = (wave >= 2);
    const u16* src = isB ? W : A;
    const int srcld = isB ? K : lda;
    const int rowbase = (isB ? tN : tM) + (wave & 1) * 64 + (lane >> 2);
    const int colofs = (lane & 3) * 8;
    const u16* gptr[4];
    u16* ldst[4];
#pragma unroll
    for (int i = 0; i < 4; ++i) {
        gptr[i] = src + (size_t)(rowbase + i * 16) * srcld + colofs;
        ldst[i] = &lAB[(wave * 4 + i) * 512];
    }

    const u16* lA = lAB;
    const u16* lB = lAB + BM * BK;
    int a_off[4], b_off[4];
#pragma unroll
    for (int i = 0; i < 4; ++i) {
        a_off[i] = (wr * 64 + i * 16 + l16) * BK + quad * 8;
        b_off[i] = (wc * 64 + i * 16 + l16) * BK + quad * 8;
    }

    f32x4 acc[4][4] = {};

    for (int kt = 0; kt < K; kt += BK) {
#pragma unroll
        for (int i = 0; i < 4; ++i) async16(gptr[i] + kt, ldst[i]);
        __syncthreads();  // drains vmcnt(0) before barrier
        bf16x8 af[4], bfr[4];
#pragma unroll
        for (int i = 0; i < 4; ++i) af[i] = *(const bf16x8*)&lA[a_off[i]];
#pragma unroll
        for (int i = 0; i < 4; ++i) bfr[i] = *(const bf16x8*)&lB[b_off[i]];
#pragma unroll
        for (int mi = 0; mi < 4; ++mi)
#pragma unroll
            for (int ni = 0; ni < 4; ++ni)
                acc[mi][ni] = __builtin_amdgcn_mfma_f32_16x16x32_bf16(
                    af[mi], bfr[ni], acc[mi][ni], 0, 0, 0);
        __syncthreads();
    }

    // epilogue: D row = quad*4+r, col = l16 (within each 16x16)
#pragma unroll
    for (int mi = 0; mi < 4; ++mi) {
#pragma unroll
        for (int ni = 0; ni < 4; ++ni) {
            int col = tN + wc * 64 + ni * 16 + l16;
            float bv = bias[col];
#pragma unroll
            for (int r = 0; r < 4; ++r) {
                int row = tM + wr * 64 + mi * 16 + quad * 4 + r;
                float v = acc[mi][ni][r] + bv;
                size_t idx = (size_t)row * ldc + col;
                if constexpr (EPI == 0) {
                    ((u16*)C)[idx] = f2bf(v);
                } else if constexpr (EPI == 1) {
                    float sp = log1pf(__expf(fminf(v, 20.f)));
                    if (v > 20.f) sp = v;
                    ((u16*)C)[idx] = f2bf(fminf(sp, 1.0f));
                } else {
                    ((float*)C)[idx] = v + resid[idx];
                }
            }
        }
    }
}

// ---------- P[t,n] = (x_ssm . W_B[n] + b_B[n]) * (x_ssm . W_C[n] + b_C[n]) ----------
// 4 tokens per block; x rows staged in LDS fp32; each wave handles 8 of the 32 dots.
__global__ __launch_bounds__(256) void bc_kernel(const u16* __restrict__ xz,
                                                 const float* __restrict__ WB,
                                                 const float* __restrict__ WC,
                                                 const float* __restrict__ bB,
                                                 const float* __restrict__ bC,
                                                 float* __restrict__ P) {
    __shared__ float xs[4][DIM];   // 32 KB
    __shared__ float dots[4][32];
    int t0 = blockIdx.x * 4, tid = threadIdx.x;
    int wave = tid >> 6, lane = tid & 63;
    for (int tk = 0; tk < 4; ++tk)
#pragma unroll
        for (int j = 0; j < 8; ++j)
            xs[tk][j * 256 + tid] = b2f(xz[(size_t)(t0 + tk) * 4096 + j * 256 + tid]);
    __syncthreads();
    for (int i = 0; i < 8; ++i) {
        int r = wave * 8 + i;  // 0..31
        const float* wrow = (r < 16) ? (WB + (size_t)r * DIM) : (WC + (size_t)(r - 16) * DIM);
        float w[32];
#pragma unroll
        for (int j = 0; j < 32; ++j) w[j] = wrow[j * 64 + lane];
        for (int tk = 0; tk < 4; ++tk) {
            float p = 0.f;
#pragma unroll
            for (int j = 0; j < 32; ++j) p += w[j] * xs[tk][j * 64 + lane];
#pragma unroll
            for (int o = 32; o; o >>= 1) p += __shfl_xor(p, o);
            if (lane == 0) dots[tk][r] = p;
        }
    }
    __syncthreads();
    if (tid < 64) {
        int tk = tid >> 4, n = tid & 15;
        P[(size_t)(t0 + tk) * 16 + n] =
            (dots[tk][n] + bB[n]) * (dots[tk][n + 16] + bC[n]);
    }
}

// ---------- y = xs * sum_n P[n]*exp(A[n,d]*dt[d]);  gated = y * silu(z) ----------
__global__ __launch_bounds__(256) void ssm_gate_kernel(const u16* __restrict__ dtb,
                                                       const u16* __restrict__ xz,
                                                       const float* __restrict__ A,
                                                       const float* __restrict__ P,
                                                       u16* __restrict__ gated) {
    __shared__ float Pl[16];
    int t = blockIdx.x, tid = threadIdx.x;
    if (tid < 16) Pl[tid] = P[(size_t)t * 16 + tid];
    __syncthreads();
    size_t xbase = (size_t)t * 4096;
    size_t dbase = (size_t)t * DIM;
#pragma unroll
    for (int j = 0; j < 8; ++j) {
        int d = j * 256 + tid;
        float dtv = b2f(dtb[dbase + d]);
        float xsv = b2f(xz[xbase + d]);
        float zv  = b2f(xz[xbase + DIM + d]);
        float s = 0.f;
#pragma unroll
        for (int n = 0; n < 16; ++n) s += Pl[n] * __expf(A[n * DIM + d] * dtv);
        float y = s * xsv;
        float sz = zv * (1.0f / (1.0f + __expf(-zv)));
        gated[dbase + d] = f2bf(y * sz);
    }
}

// ---------- launch ----------
extern "C" void kernel_launch(void* const* d_in, const int* in_sizes, int n_in,
                              void* d_out, int out_size, void* d_ws, size_t ws_size,
                              hipStream_t stream) {
    const float* x      = (const float*)d_in[0];
    const float* ln_g   = (const float*)d_in[1];
    const float* ln_b   = (const float*)d_in[2];
    const float* W_in   = (const float*)d_in[3];
    const float* b_in   = (const float*)d_in[4];
    const float* stateA = (const float*)d_in[5];
    const float* W_B    = (const float*)d_in[6];
    const float* b_B    = (const float*)d_in[7];
    const float* W_C    = (const float*)d_in[8];
    const float* b_C    = (const float*)d_in[9];
    const float* W_dt   = (const float*)d_in[10];
    const float* b_dt   = (const float*)d_in[11];
    const float* W_out  = (const float*)d_in[12];
    const float* b_out  = (const float*)d_in[13];

    char* ws = (char*)d_ws;
    u16*   wbuf = (u16*)(ws);                         // 16 MB (max 8.39M bf16)
    u16*   xnb  = (u16*)(ws + 16777216);              // 16 MB  (T x D; reused as gated)
    u16*   xzb  = (u16*)(ws + 33554432);              // 32 MB  (T x 2D)
    u16*   dtb  = (u16*)(ws + 67108864);              // 16 MB  (T x D)
    float* Pbuf = (float*)(ws + 83886080);            // 256 KB (T x 16)

    // 1. W_in -> bf16   (8,388,608 elems)
    castw_kernel<<<8192, 256, 0, stream>>>(W_in, wbuf, 2097152);
    // 2. LN(x) -> bf16
    ln_cast_kernel<<<T_TOK, 256, 0, stream>>>(x, ln_g, ln_b, xnb);
    // 3. xz = xn @ W_in^T + b_in   (T x 4096, bf16)
    gemm_bt<0><<<dim3(32, 32), 256, 0, stream>>>(xnb, 2048, wbuf, b_in, nullptr,
                                                 xzb, 4096, 2048);
    // 4. W_dt -> bf16   (4,194,304 elems)
    castw_kernel<<<4096, 256, 0, stream>>>(W_dt, wbuf, 1048576);
    // 5. dt = min(softplus(x_ssm @ W_dt^T + b_dt), 1)   (T x 2048, bf16)
    gemm_bt<1><<<dim3(32, 16), 256, 0, stream>>>(xzb, 4096, wbuf, b_dt, nullptr,
                                                 dtb, 2048, 2048);
    // 6. P[t,n] = Bm*Cm
    bc_kernel<<<1024, 256, 0, stream>>>(xzb, W_B, W_C, b_B, b_C, Pbuf);
    // 7. gated (reuse xnb)
    ssm_gate_kernel<<<T_TOK, 256, 0, stream>>>(dtb, xzb, stateA, Pbuf, xnb);
    // 8. W_out -> bf16
    castw_kernel<<<4096, 256, 0, stream>>>(W_out, wbuf, 1048576);
    // 9. out = gated @ W_out^T + b_out + x   (T x 2048, f32)
    gemm_bt<2><<<dim3(32, 16), 256, 0, stream>>>(xnb, 2048, wbuf, b_out, x,
                                                 (float*)d_out, 2048, 2048);
}